// Round 10
// baseline (108.323 us; speedup 1.0000x reference)
//
#include <hip/hip_runtime.h>
#include <hip/hip_bf16.h>

// GridToMeshEncoder R10: producer/consumer wave-specialized fused kernel.
// 512 threads: waves 0-3 gather (R5 phase-1 code), waves 4-7 GEMM (R5 phases
// 2-3 code). comb double-buffered; per tile: alpha {gemm1 || load rows(j+1)},
// beta {gemm2 || reduce->nxt}. Memory ops issue in every phase -> no burst-
// dead-burst duty-cycle loss. Persistent-ish grid: 512 blocks x 2-3 tiles.

constexpr int kNLat  = 721;
constexpr int kNLon  = 1440;
constexpr long long kNPix = (long long)kNLat * kNLon;   // 1038240
constexpr int kMesh  = 40962;
constexpr int kCIn   = 64;
constexpr int kFeat  = 4;
constexpr int kDIn   = kCIn + kFeat;                    // 68
constexpr int kHid   = 256;
constexpr int kOut   = 256;
constexpr int kBatch = 2;

constexpr int kPts    = kBatch * kMesh;                 // 81924
constexpr int kPtsPad = (kPts + 63) & ~63;              // 81984

typedef __attribute__((ext_vector_type(8))) short bf16x8;
typedef __attribute__((ext_vector_type(4))) float f32x4;

// ws layout (ushort units): wsA1 = W1^T A-frags [rt:16][ks:3][lane:64][j:8]
//                           wsB2 = W2   frags   [ct:16][ks:8][lane:64][j:8]
constexpr int    WSA1_N   = 16 * 3 * 64 * 8;            // 24576
constexpr int    WSB2_N   = 16 * 8 * 64 * 8;            // 65536
constexpr size_t WS_BYTES = (size_t)(WSA1_N + WSB2_N) * 2;  // 180224

constexpr int MP     = 64;                      // points per tile
constexpr int NTILES = kPtsPad / MP;            // 1281
constexpr int NBLK   = 512;                     // persistent blocks (2/CU)
constexpr int CSTR   = 104;                     // comb row stride (R5-proven)
constexpr int HSTR   = 264;                     // hbuf row stride (R5-proven)

__device__ inline ushort f2b(float v) {
    __hip_bfloat16 h = __float2bfloat16(v);
    return *reinterpret_cast<ushort*>(&h);
}

// ---------------- prep: pack W1/W2 into frag-ordered bf16 ----------------
__global__ __launch_bounds__(256)
void g2m_prep(const float* __restrict__ W1, const float* __restrict__ W2,
              ushort* __restrict__ ws) {
    const int tid = blockIdx.x * 256 + threadIdx.x;
    if (tid < 3072) {                       // wsA1: A[i=hid][k] = W1[k][hid]
        const int l  = tid & 63;
        const int g  = tid >> 6;            // g = rt*3 + ks
        const int ks = g % 3;
        const int rt = g / 3;
        const int hid = rt * 16 + (l & 15);
        const int k0  = ks * 32 + (l >> 4) * 8;
        ushort tmp[8];
        #pragma unroll
        for (int j = 0; j < 8; ++j) {
            const int k = k0 + j;
            tmp[j] = f2b(k < kDIn ? W1[(size_t)k * kHid + hid] : 0.f);
        }
        *reinterpret_cast<bf16x8*>(ws + (size_t)tid * 8) =
            *reinterpret_cast<bf16x8*>(tmp);
    } else if (tid < 11264) {               // wsB2: [ct][ks][lane][8] = W2[k][col]
        const int q  = tid - 3072;
        const int l  = q & 63;
        const int g  = q >> 6;              // g = ct*8 + ks
        const int ks = g % 8;
        const int ct = g / 8;
        const int col = ct * 16 + (l & 15);
        const int k0  = ks * 32 + (l >> 4) * 8;
        ushort tmp[8];
        #pragma unroll
        for (int j = 0; j < 8; ++j) {
            const int k = k0 + j;
            tmp[j] = f2b(W2[(size_t)k * kOut + col]);
        }
        *reinterpret_cast<bf16x8*>(ws + (size_t)(WSA1_N + q * 8)) =
            *reinterpret_cast<bf16x8*>(tmp);
    }
}

// ---------------- producer helpers (R5 phase-1 bodies) ----------------
struct PState {
    float4 rr[4][4];    // [it][corner]
    float4 wt[4];
    float  mf0[4], mf1[4];
};

__device__ inline void prod_load(const float* __restrict__ grid,
                                 const float* __restrict__ mfeat,
                                 const int*   __restrict__ indices,
                                 const float* __restrict__ weights,
                                 int p0, int pw, int l15, int l4, PState& s) {
    #pragma unroll
    for (int it = 0; it < 4; ++it) {
        const int p = p0 + pw * 16 + it * 4 + l4;
        s.rr[it][0] = s.rr[it][1] = s.rr[it][2] = s.rr[it][3] = float4{0.f, 0.f, 0.f, 0.f};
        s.wt[it] = float4{0.f, 0.f, 0.f, 0.f};
        s.mf0[it] = 0.f; s.mf1[it] = 0.f;
        if (p < kPts) {
            const int b = (p >= kMesh) ? 1 : 0;
            const int m = p - b * kMesh;
            const int4 id = *reinterpret_cast<const int4*>(indices + (size_t)m * 4);
            s.wt[it] = *reinterpret_cast<const float4*>(weights + (size_t)m * 4);
            const float* gb = grid + (size_t)b * (size_t)(kNPix * kCIn);
            s.rr[it][0] = *reinterpret_cast<const float4*>(gb + (size_t)id.x * kCIn + l15 * 4);
            s.rr[it][1] = *reinterpret_cast<const float4*>(gb + (size_t)id.y * kCIn + l15 * 4);
            s.rr[it][2] = *reinterpret_cast<const float4*>(gb + (size_t)id.z * kCIn + l15 * 4);
            s.rr[it][3] = *reinterpret_cast<const float4*>(gb + (size_t)id.w * kCIn + l15 * 4);
            if (l15 < 2) {
                s.mf0[it] = mfeat[(size_t)m * kFeat + l15 * 2];
                s.mf1[it] = mfeat[(size_t)m * kFeat + l15 * 2 + 1];
            }
        }
    }
}

__device__ inline void prod_reduce(const PState& s, ushort* comb,
                                   int pw, int l15, int l4) {
    #pragma unroll
    for (int it = 0; it < 4; ++it) {
        const int row = pw * 16 + it * 4 + l4;
        const float4 wt = s.wt[it];
        float4 acc;
        acc.x = fmaf(wt.x, s.rr[it][0].x, fmaf(wt.y, s.rr[it][1].x, fmaf(wt.z, s.rr[it][2].x, wt.w * s.rr[it][3].x)));
        acc.y = fmaf(wt.x, s.rr[it][0].y, fmaf(wt.y, s.rr[it][1].y, fmaf(wt.z, s.rr[it][2].y, wt.w * s.rr[it][3].y)));
        acc.z = fmaf(wt.x, s.rr[it][0].z, fmaf(wt.y, s.rr[it][1].z, fmaf(wt.z, s.rr[it][2].z, wt.w * s.rr[it][3].z)));
        acc.w = fmaf(wt.x, s.rr[it][0].w, fmaf(wt.y, s.rr[it][1].w, fmaf(wt.z, s.rr[it][2].w, wt.w * s.rr[it][3].w)));
        ushort4 pk;
        pk.x = f2b(acc.x); pk.y = f2b(acc.y); pk.z = f2b(acc.z); pk.w = f2b(acc.w);
        *reinterpret_cast<ushort4*>(&comb[row * CSTR + l15 * 4]) = pk;     // 0..63
        ushort2 ft;                                                         // 64..95
        ft.x = f2b(s.mf0[it]); ft.y = f2b(s.mf1[it]);
        *reinterpret_cast<ushort2*>(&comb[row * CSTR + 64 + l15 * 2]) = ft;
        if (l15 < (CSTR - kDIn) / 2 && l15 >= 0) { /* K-pad below */ }
        // zero K-pad cols 68..95 handled by mf writes? No: cols 68..95 pad.
    }
    // zero K-pad (cols 68..CSTR-usedK): GEMM1 reads k up to 96; cols 68..95 must be 0.
    #pragma unroll
    for (int it = 0; it < 4; ++it) {
        const int row = pw * 16 + it * 4 + l4;
        if (l15 < 14) comb[row * CSTR + 68 + l15 * 2] = 0;
        if (l15 < 14) comb[row * CSTR + 69 + l15 * 2] = 0;
    }
}

// ---------------- consumer helpers (R5 phase-2/3 bodies) ----------------
__device__ inline void gemm1(const ushort* comb, ushort* hbuf,
                             const ushort* __restrict__ ws,
                             const float* __restrict__ b1,
                             int cw, int lane, int l15, int l4) {
    f32x4 acc1[4][4];
    #pragma unroll
    for (int r = 0; r < 4; ++r)
        #pragma unroll
        for (int mt = 0; mt < 4; ++mt) acc1[r][mt] = (f32x4)0.f;

    #pragma unroll
    for (int ks = 0; ks < 3; ++ks) {
        bf16x8 af[4], bfr[4];
        #pragma unroll
        for (int r = 0; r < 4; ++r) {
            const int rt = cw * 4 + r;
            af[r] = *reinterpret_cast<const bf16x8*>(
                        ws + (size_t)((rt * 3 + ks) * 64 + lane) * 8);
        }
        #pragma unroll
        for (int mt = 0; mt < 4; ++mt)
            bfr[mt] = *reinterpret_cast<const bf16x8*>(
                        &comb[(mt * 16 + l15) * CSTR + ks * 32 + l4 * 8]);
        #pragma unroll
        for (int r = 0; r < 4; ++r)
            #pragma unroll
            for (int mt = 0; mt < 4; ++mt)
                acc1[r][mt] = __builtin_amdgcn_mfma_f32_16x16x32_bf16(
                                  af[r], bfr[mt], acc1[r][mt], 0, 0, 0);
    }

    #pragma unroll
    for (int r = 0; r < 4; ++r) {
        const int hid0 = (cw * 4 + r) * 16 + l4 * 4;
        const float4 bv = *reinterpret_cast<const float4*>(b1 + hid0);
        #pragma unroll
        for (int mt = 0; mt < 4; ++mt) {
            const int m = mt * 16 + l15;
            ushort4 hv;
            hv.x = f2b(fmaxf(acc1[r][mt][0] + bv.x, 0.f));
            hv.y = f2b(fmaxf(acc1[r][mt][1] + bv.y, 0.f));
            hv.z = f2b(fmaxf(acc1[r][mt][2] + bv.z, 0.f));
            hv.w = f2b(fmaxf(acc1[r][mt][3] + bv.w, 0.f));
            *reinterpret_cast<ushort4*>(&hbuf[m * HSTR + hid0]) = hv;
        }
    }
}

__device__ inline void gemm2(const ushort* hbuf,
                             const ushort* __restrict__ ws,
                             const float* __restrict__ b2,
                             float* __restrict__ out,
                             int p0, int cw, int lane, int l15, int l4) {
    f32x4 acc2[4][4];
    #pragma unroll
    for (int mt = 0; mt < 4; ++mt)
        #pragma unroll
        for (int c = 0; c < 4; ++c) acc2[mt][c] = (f32x4)0.f;

    #pragma unroll
    for (int ks = 0; ks < 8; ++ks) {
        bf16x8 hf[4], wf[4];
        #pragma unroll
        for (int mt = 0; mt < 4; ++mt)
            hf[mt] = *reinterpret_cast<const bf16x8*>(
                        &hbuf[(mt * 16 + l15) * HSTR + ks * 32 + l4 * 8]);
        #pragma unroll
        for (int c = 0; c < 4; ++c) {
            const int ct = cw * 4 + c;
            wf[c] = *reinterpret_cast<const bf16x8*>(
                        ws + (size_t)(WSA1_N + ((ct * 8 + ks) * 64 + lane) * 8));
        }
        #pragma unroll
        for (int mt = 0; mt < 4; ++mt)
            #pragma unroll
            for (int c = 0; c < 4; ++c)
                acc2[mt][c] = __builtin_amdgcn_mfma_f32_16x16x32_bf16(
                                  wf[c], hf[mt], acc2[mt][c], 0, 0, 0);
    }

    #pragma unroll
    for (int c = 0; c < 4; ++c) {
        const int col0 = (cw * 4 + c) * 16 + l4 * 4;
        const float4 bv = *reinterpret_cast<const float4*>(b2 + col0);
        #pragma unroll
        for (int mt = 0; mt < 4; ++mt) {
            const int p = p0 + mt * 16 + l15;
            if (p < kPts) {
                float4 o;
                o.x = acc2[mt][c][0] + bv.x;
                o.y = acc2[mt][c][1] + bv.y;
                o.z = acc2[mt][c][2] + bv.z;
                o.w = acc2[mt][c][3] + bv.w;
                *reinterpret_cast<float4*>(out + (size_t)p * kOut + col0) = o;
            }
        }
    }
}

// ---------------- producer/consumer fused kernel ----------------
__global__ __launch_bounds__(512, 2)
void g2m_pc(const float* __restrict__ grid,
            const float* __restrict__ mfeat,
            const int*   __restrict__ indices,
            const float* __restrict__ weights,
            const float* __restrict__ b1,
            const float* __restrict__ b2,
            const ushort* __restrict__ ws,
            float* __restrict__ out)
{
    __shared__ __align__(16) ushort combA[MP * CSTR];   // 13312 B
    __shared__ __align__(16) ushort combB[MP * CSTR];   // 13312 B
    __shared__ __align__(16) ushort hbuf[MP * HSTR];    // 33792 B

    const int t    = threadIdx.x;
    const int lane = t & 63;
    const int wv   = t >> 6;                // 0..7
    const bool isP = wv < 4;
    const int rw   = wv & 3;                // role-wave id 0..3
    const int l15  = lane & 15;
    const int l4   = lane >> 4;
    const int bid  = blockIdx.x;
    const int nt   = (bid < NTILES - 2 * NBLK) ? 3 : 2;   // 257 blocks get 3 tiles

    PState s;

    if (isP) {
        prod_load(grid, mfeat, indices, weights, bid * MP, rw, l15, l4, s);
        prod_reduce(s, combA, rw, l15, l4);
    }
    __syncthreads();                        // combA(T0) ready

    for (int j = 0; j < nt; ++j) {
        ushort* cur = (j & 1) ? combB : combA;
        ushort* nxt = (j & 1) ? combA : combB;
        const int p0 = (bid + j * NBLK) * MP;

        // alpha: gemm1 || issue next-tile loads
        if (isP) {
            if (j + 1 < nt)
                prod_load(grid, mfeat, indices, weights,
                          (bid + (j + 1) * NBLK) * MP, rw, l15, l4, s);
        } else {
            gemm1(cur, hbuf, ws, b1, rw, lane, l15, l4);
        }
        __syncthreads();                    // hbuf ready; cur fully read

        // beta: gemm2 -> out || reduce -> nxt
        if (isP) {
            if (j + 1 < nt)
                prod_reduce(s, nxt, rw, l15, l4);
        } else {
            gemm2(hbuf, ws, b2, out, p0, rw, lane, l15, l4);
        }
        __syncthreads();                    // nxt ready; hbuf fully read
    }
}

extern "C" void kernel_launch(void* const* d_in, const int* in_sizes, int n_in,
                              void* d_out, int out_size, void* d_ws, size_t ws_size,
                              hipStream_t stream) {
    const float* grid    = (const float*)d_in[0];
    const float* mfeat   = (const float*)d_in[1];
    const int*   indices = (const int*)d_in[2];
    const float* weights = (const float*)d_in[3];
    const float* W1      = (const float*)d_in[4];
    const float* b1      = (const float*)d_in[5];
    const float* W2      = (const float*)d_in[6];
    const float* b2      = (const float*)d_in[7];
    float* o = (float*)d_out;

    if (ws_size >= WS_BYTES) {
        ushort* ws = (ushort*)d_ws;
        g2m_prep<<<44, 256, 0, stream>>>(W1, W2, ws);
        g2m_pc<<<NBLK, 512, 0, stream>>>(grid, mfeat, indices, weights,
                                         b1, b2, ws, o);
    }
}

// Round 12
// 66.995 us; speedup vs baseline: 1.6169x; 1.6169x over previous
//
#include <hip/hip_runtime.h>
#include <hip/hip_bf16.h>

// GridToMeshEncoder R11b: barrier-free per-wave pipeline (R11 + compile fix:
// nontemporal store via ext_vector f32x4 instead of HIP float4 class).
// Each wave owns 16 mesh points end-to-end in a private 8KB LDS slice:
//   gather -> comb(slice) -> B-frags(regs) -> GEMM1 (16 hid-tiles, A from L2 ws)
//   -> hbuf(same slice) -> GEMM2 (16 outcol-tiles) -> nontemporal f32x4 out.
// NO __syncthreads anywhere; waves self-pace so memory ops issue continuously.

constexpr int kNLat  = 721;
constexpr int kNLon  = 1440;
constexpr long long kNPix = (long long)kNLat * kNLon;   // 1038240
constexpr int kMesh  = 40962;
constexpr int kCIn   = 64;
constexpr int kFeat  = 4;
constexpr int kDIn   = kCIn + kFeat;                    // 68
constexpr int kHid   = 256;
constexpr int kOut   = 256;
constexpr int kBatch = 2;

constexpr int kPts    = kBatch * kMesh;                 // 81924
constexpr int kPtsPad = (kPts + 63) & ~63;              // 81984

typedef __attribute__((ext_vector_type(8))) short bf16x8;
typedef __attribute__((ext_vector_type(4))) float f32x4;

// ws layout (ushort units): wsA1 = W1^T A-frags [rt:16][ks:3][lane:64][j:8]
//                           wsB2 = W2   frags   [ct:16][ks:8][lane:64][j:8]
constexpr int    WSA1_N   = 16 * 3 * 64 * 8;            // 24576
constexpr int    WSB2_N   = 16 * 8 * 64 * 8;            // 65536
constexpr size_t WS_BYTES = (size_t)(WSA1_N + WSB2_N) * 2;  // 180224

constexpr int NBLKB = kPtsPad / 64;             // 1281 (64 pts per block, 16/wave)
constexpr int HSTR  = 256;                      // slice row stride (ushort): 512 B

__device__ inline ushort f2b(float v) {
    __hip_bfloat16 h = __float2bfloat16(v);
    return *reinterpret_cast<ushort*>(&h);
}

// XOR swizzle on 16B granules within a 512B row (R6-validated, write/read paired)
__device__ inline int swz(int r, int c) { return r * HSTR + (c ^ ((r & 7) << 3)); }

// ---------------- prep: pack W1/W2 into frag-ordered bf16 ----------------
__global__ __launch_bounds__(256)
void g2m_prep(const float* __restrict__ W1, const float* __restrict__ W2,
              ushort* __restrict__ ws) {
    const int tid = blockIdx.x * 256 + threadIdx.x;
    if (tid < 3072) {                       // wsA1: A[i=hid][k] = W1[k][hid]
        const int l  = tid & 63;
        const int g  = tid >> 6;            // g = rt*3 + ks
        const int ks = g % 3;
        const int rt = g / 3;
        const int hid = rt * 16 + (l & 15);
        const int k0  = ks * 32 + (l >> 4) * 8;
        ushort tmp[8];
        #pragma unroll
        for (int j = 0; j < 8; ++j) {
            const int k = k0 + j;
            tmp[j] = f2b(k < kDIn ? W1[(size_t)k * kHid + hid] : 0.f);
        }
        *reinterpret_cast<bf16x8*>(ws + (size_t)tid * 8) =
            *reinterpret_cast<bf16x8*>(tmp);
    } else if (tid < 11264) {               // wsB2: [ct][ks][lane][8] = W2[k][col]
        const int q  = tid - 3072;
        const int l  = q & 63;
        const int g  = q >> 6;              // g = ct*8 + ks
        const int ks = g % 8;
        const int ct = g / 8;
        const int col = ct * 16 + (l & 15);
        const int k0  = ks * 32 + (l >> 4) * 8;
        ushort tmp[8];
        #pragma unroll
        for (int j = 0; j < 8; ++j) {
            const int k = k0 + j;
            tmp[j] = f2b(W2[(size_t)k * kOut + col]);
        }
        *reinterpret_cast<bf16x8*>(ws + (size_t)(WSA1_N + q * 8)) =
            *reinterpret_cast<bf16x8*>(tmp);
    }
}

// ---------------- barrier-free per-wave fused kernel ----------------
__global__ __launch_bounds__(256, 4)
void g2m_wave(const float* __restrict__ grid,
              const float* __restrict__ mfeat,
              const int*   __restrict__ indices,
              const float* __restrict__ weights,
              const float* __restrict__ b1,
              const float* __restrict__ b2,
              const ushort* __restrict__ ws,
              float* __restrict__ out)
{
    __shared__ __align__(16) ushort lds[4][16 * HSTR];  // 4 x 8192 B = 32 KB

    const int t    = threadIdx.x;
    const int lane = t & 63;
    const int w    = t >> 6;                    // wave id 0..3
    const int l15  = lane & 15;
    const int l4   = lane >> 4;
    const int p0   = blockIdx.x * 64 + w * 16;  // this wave's 16 points
    ushort* my = lds[w];                        // private slice

    // ---- phase A: gather 16 points (4 iters x 4 pts), reduce -> comb ----
    {
        const int q = l4;                       // point-in-group 0..3
        #pragma unroll
        for (int it = 0; it < 4; ++it) {
            const int row = it * 4 + q;         // local pt 0..15
            const int p   = p0 + row;
            float4 acc = {0.f, 0.f, 0.f, 0.f};
            float mf0 = 0.f, mf1 = 0.f;
            if (p < kPts) {
                const int b = (p >= kMesh) ? 1 : 0;
                const int m = p - b * kMesh;
                const int4   id = *reinterpret_cast<const int4*>(indices + (size_t)m * 4);
                const float4 wt = *reinterpret_cast<const float4*>(weights + (size_t)m * 4);
                const float* gb = grid + (size_t)b * (size_t)(kNPix * kCIn);
                const float4 r0 = *reinterpret_cast<const float4*>(gb + (size_t)id.x * kCIn + l15 * 4);
                const float4 r1 = *reinterpret_cast<const float4*>(gb + (size_t)id.y * kCIn + l15 * 4);
                const float4 r2 = *reinterpret_cast<const float4*>(gb + (size_t)id.z * kCIn + l15 * 4);
                const float4 r3 = *reinterpret_cast<const float4*>(gb + (size_t)id.w * kCIn + l15 * 4);
                acc.x = fmaf(wt.x, r0.x, fmaf(wt.y, r1.x, fmaf(wt.z, r2.x, wt.w * r3.x)));
                acc.y = fmaf(wt.x, r0.y, fmaf(wt.y, r1.y, fmaf(wt.z, r2.y, wt.w * r3.y)));
                acc.z = fmaf(wt.x, r0.z, fmaf(wt.y, r1.z, fmaf(wt.z, r2.z, wt.w * r3.z)));
                acc.w = fmaf(wt.x, r0.w, fmaf(wt.y, r1.w, fmaf(wt.z, r2.w, wt.w * r3.w)));
                if (l15 < 2) {
                    mf0 = mfeat[(size_t)m * kFeat + l15 * 2];
                    mf1 = mfeat[(size_t)m * kFeat + l15 * 2 + 1];
                }
            }
            ushort4 pk;
            pk.x = f2b(acc.x); pk.y = f2b(acc.y); pk.z = f2b(acc.z); pk.w = f2b(acc.w);
            *reinterpret_cast<ushort4*>(&my[swz(row, l15 * 4)]) = pk;     // cols 0..63
            ushort2 ft;                                                    // cols 64..95 (zeros beyond 67)
            ft.x = f2b(mf0); ft.y = f2b(mf1);
            *reinterpret_cast<ushort2*>(&my[swz(row, 64 + l15 * 2)]) = ft;
        }
    }

    // ---- read GEMM1 B-frags (consumes comb fully; slice then reusable) ----
    bf16x8 bfr[3];
    #pragma unroll
    for (int ks = 0; ks < 3; ++ks)
        bfr[ks] = *reinterpret_cast<const bf16x8*>(&my[swz(l15, ks * 32 + l4 * 8)]);

    // ---- phase B: GEMM1  h^T = W1^T @ comb^T, 16 hid-tiles ----
    #pragma unroll 4
    for (int rt = 0; rt < 16; ++rt) {
        f32x4 acc = (f32x4)0.f;
        #pragma unroll
        for (int ks = 0; ks < 3; ++ks) {
            const bf16x8 af = *reinterpret_cast<const bf16x8*>(
                    ws + (size_t)((rt * 3 + ks) * 64 + lane) * 8);
            acc = __builtin_amdgcn_mfma_f32_16x16x32_bf16(af, bfr[ks], acc, 0, 0, 0);
        }
        const int hid0 = rt * 16 + l4 * 4;
        const float4 bv = *reinterpret_cast<const float4*>(b1 + hid0);
        ushort4 hv;
        hv.x = f2b(fmaxf(acc[0] + bv.x, 0.f));
        hv.y = f2b(fmaxf(acc[1] + bv.y, 0.f));
        hv.z = f2b(fmaxf(acc[2] + bv.z, 0.f));
        hv.w = f2b(fmaxf(acc[3] + bv.w, 0.f));
        *reinterpret_cast<ushort4*>(&my[swz(l15, hid0)]) = hv;   // hbuf overwrites comb (dead)
    }

    // ---- read GEMM2 B-frags (h for this wave's 16 points) ----
    bf16x8 hf[8];
    #pragma unroll
    for (int ks = 0; ks < 8; ++ks)
        hf[ks] = *reinterpret_cast<const bf16x8*>(&my[swz(l15, ks * 32 + l4 * 8)]);

    // ---- phase C: GEMM2^T  out^T = W2^T @ h^T, 16 outcol-tiles ----
    const int p   = p0 + l15;
    const bool ok = (p < kPts);
    float* obase  = out + (size_t)p * kOut;
    #pragma unroll 2
    for (int ct = 0; ct < 16; ++ct) {
        f32x4 acc = (f32x4)0.f;
        #pragma unroll
        for (int ks = 0; ks < 8; ++ks) {
            const bf16x8 wf = *reinterpret_cast<const bf16x8*>(
                    ws + (size_t)(WSA1_N + ((ct * 8 + ks) * 64 + lane) * 8));
            acc = __builtin_amdgcn_mfma_f32_16x16x32_bf16(wf, hf[ks], acc, 0, 0, 0);
        }
        const int col0 = ct * 16 + l4 * 4;
        const float4 bv = *reinterpret_cast<const float4*>(b2 + col0);
        if (ok) {
            f32x4 o;
            o[0] = acc[0] + bv.x;
            o[1] = acc[1] + bv.y;
            o[2] = acc[2] + bv.z;
            o[3] = acc[3] + bv.w;
            __builtin_nontemporal_store(o, reinterpret_cast<f32x4*>(obase + col0));
        }
    }
}

extern "C" void kernel_launch(void* const* d_in, const int* in_sizes, int n_in,
                              void* d_out, int out_size, void* d_ws, size_t ws_size,
                              hipStream_t stream) {
    const float* grid    = (const float*)d_in[0];
    const float* mfeat   = (const float*)d_in[1];
    const int*   indices = (const int*)d_in[2];
    const float* weights = (const float*)d_in[3];
    const float* W1      = (const float*)d_in[4];
    const float* b1      = (const float*)d_in[5];
    const float* W2      = (const float*)d_in[6];
    const float* b2      = (const float*)d_in[7];
    float* o = (float*)d_out;

    if (ws_size >= WS_BYTES) {
        ushort* ws = (ushort*)d_ws;
        g2m_prep<<<44, 256, 0, stream>>>(W1, W2, ws);
        g2m_wave<<<NBLKB, 256, 0, stream>>>(grid, mfeat, indices, weights,
                                            b1, b2, ws, o);
    }
}

// Round 13
// 53.034 us; speedup vs baseline: 2.0425x; 1.2632x over previous
//
#include <hip/hip_runtime.h>
#include <hip/hip_bf16.h>

// GridToMeshEncoder R12: exact R5 fused kernel + deterministic entry stagger
// ((blockIdx%3) x s_sleep(127) ~ 3.4us steps) to break the chip-wide
// gather/compute convoy (HBM contention phase-locks same-phase blocks).
//   phase1: vectorized gather -> comb LDS
//   phase2: GEMM1 h^T = W1^T * comb^T -> hbuf LDS
//   phase3: GEMM2^T out^T = W2^T * h^T -> float4 stores
// prep kernel packs W1/W2 into MFMA fragment order (L2-resident, ~180 KB).

constexpr int kNLat  = 721;
constexpr int kNLon  = 1440;
constexpr long long kNPix = (long long)kNLat * kNLon;   // 1038240
constexpr int kMesh  = 40962;
constexpr int kCIn   = 64;
constexpr int kFeat  = 4;
constexpr int kDIn   = kCIn + kFeat;                    // 68
constexpr int kHid   = 256;
constexpr int kOut   = 256;
constexpr int kBatch = 2;

constexpr int kPts    = kBatch * kMesh;                 // 81924
constexpr int kPtsPad = (kPts + 63) & ~63;              // 81984

typedef __attribute__((ext_vector_type(8))) short bf16x8;
typedef __attribute__((ext_vector_type(4))) float f32x4;

// ws layout (ushort units): wsA1 = W1^T A-frags [rt:16][ks:3][lane:64][j:8]
//                           wsB2 = W2   frags   [ct:16][ks:8][lane:64][j:8]
constexpr int    WSA1_N   = 16 * 3 * 64 * 8;            // 24576
constexpr int    WSB2_N   = 16 * 8 * 64 * 8;            // 65536
constexpr size_t WS_BYTES = (size_t)(WSA1_N + WSB2_N) * 2;  // 180224

constexpr int MP    = 64;                       // points per block
constexpr int NBLKB = kPtsPad / MP;             // 1281
constexpr int CSTR  = 104;                      // comb row stride (bf16)
constexpr int HSTR  = 264;                      // hbuf row stride (bf16)

__device__ inline ushort f2b(float v) {
    __hip_bfloat16 h = __float2bfloat16(v);
    return *reinterpret_cast<ushort*>(&h);
}

// ---------------- prep: pack W1/W2 into frag-ordered bf16 ----------------
__global__ __launch_bounds__(256)
void g2m_prep(const float* __restrict__ W1, const float* __restrict__ W2,
              ushort* __restrict__ ws) {
    const int tid = blockIdx.x * 256 + threadIdx.x;
    if (tid < 3072) {                       // wsA1: A[i=hid][k] = W1[k][hid]
        const int l  = tid & 63;
        const int g  = tid >> 6;            // g = rt*3 + ks
        const int ks = g % 3;
        const int rt = g / 3;
        const int hid = rt * 16 + (l & 15);
        const int k0  = ks * 32 + (l >> 4) * 8;
        ushort tmp[8];
        #pragma unroll
        for (int j = 0; j < 8; ++j) {
            const int k = k0 + j;
            tmp[j] = f2b(k < kDIn ? W1[(size_t)k * kHid + hid] : 0.f);
        }
        *reinterpret_cast<bf16x8*>(ws + (size_t)tid * 8) =
            *reinterpret_cast<bf16x8*>(tmp);
    } else if (tid < 11264) {               // wsB2: [ct][ks][lane][8] = W2[k][col]
        const int q  = tid - 3072;
        const int l  = q & 63;
        const int g  = q >> 6;              // g = ct*8 + ks
        const int ks = g % 8;
        const int ct = g / 8;
        const int col = ct * 16 + (l & 15);
        const int k0  = ks * 32 + (l >> 4) * 8;
        ushort tmp[8];
        #pragma unroll
        for (int j = 0; j < 8; ++j) {
            const int k = k0 + j;
            tmp[j] = f2b(W2[(size_t)k * kOut + col]);
        }
        *reinterpret_cast<bf16x8*>(ws + (size_t)(WSA1_N + q * 8)) =
            *reinterpret_cast<bf16x8*>(tmp);
    }
}

// ---------------- fused: gather -> GEMM1 -> GEMM2^T -> out ----------------
__global__ __launch_bounds__(256, 3)
void g2m_fused2(const float* __restrict__ grid,
                const float* __restrict__ mfeat,
                const int*   __restrict__ indices,
                const float* __restrict__ weights,
                const float* __restrict__ b1,
                const float* __restrict__ b2,
                const ushort* __restrict__ ws,
                float* __restrict__ out)
{
    __shared__ __align__(16) ushort comb[MP * CSTR];    // 13312 B
    __shared__ __align__(16) ushort hbuf[MP * HSTR];    // 33792 B

    // ---- entry stagger: desynchronize block phase cohorts (0/3.4/6.8 us) ----
    {
        const int ph = blockIdx.x % 3;
        #pragma unroll 1
        for (int i = 0; i < ph; ++i) __builtin_amdgcn_s_sleep(127);
    }

    const int t    = threadIdx.x;
    const int lane = t & 63;
    const int w    = t >> 6;                    // wave id 0..3
    const int p0   = blockIdx.x * MP;
    const int l15  = lane & 15;
    const int l4   = lane >> 4;

    // ---- phase 1: vectorized gather, 4 points per wave-iteration ----
    {
        const int q = l4;                       // point-in-group 0..3
        #pragma unroll
        for (int it = 0; it < 4; ++it) {
            const int row = (w * 4 + it) * 4 + q;   // local row 0..63
            const int p   = p0 + row;
            float4 acc = {0.f, 0.f, 0.f, 0.f};
            float mf0 = 0.f, mf1 = 0.f;
            if (p < kPts) {
                const int b = (p >= kMesh) ? 1 : 0;
                const int m = p - b * kMesh;
                const int4   id = *reinterpret_cast<const int4*>(indices + (size_t)m * 4);
                const float4 wt = *reinterpret_cast<const float4*>(weights + (size_t)m * 4);
                const float* gb = grid + (size_t)b * (size_t)(kNPix * kCIn);
                const float4 r0 = *reinterpret_cast<const float4*>(gb + (size_t)id.x * kCIn + l15 * 4);
                const float4 r1 = *reinterpret_cast<const float4*>(gb + (size_t)id.y * kCIn + l15 * 4);
                const float4 r2 = *reinterpret_cast<const float4*>(gb + (size_t)id.z * kCIn + l15 * 4);
                const float4 r3 = *reinterpret_cast<const float4*>(gb + (size_t)id.w * kCIn + l15 * 4);
                acc.x = fmaf(wt.x, r0.x, fmaf(wt.y, r1.x, fmaf(wt.z, r2.x, wt.w * r3.x)));
                acc.y = fmaf(wt.x, r0.y, fmaf(wt.y, r1.y, fmaf(wt.z, r2.y, wt.w * r3.y)));
                acc.z = fmaf(wt.x, r0.z, fmaf(wt.y, r1.z, fmaf(wt.z, r2.z, wt.w * r3.z)));
                acc.w = fmaf(wt.x, r0.w, fmaf(wt.y, r1.w, fmaf(wt.z, r2.w, wt.w * r3.w)));
                if (l15 < 2) {
                    mf0 = mfeat[(size_t)m * kFeat + l15 * 2];
                    mf1 = mfeat[(size_t)m * kFeat + l15 * 2 + 1];
                }
            }
            ushort* rowp = &comb[row * CSTR];
            ushort4 pk;
            pk.x = f2b(acc.x); pk.y = f2b(acc.y); pk.z = f2b(acc.z); pk.w = f2b(acc.w);
            *reinterpret_cast<ushort4*>(rowp + l15 * 4) = pk;       // cols 0..63
            ushort2 ft;                                              // cols 64..95
            ft.x = f2b(mf0); ft.y = f2b(mf1);
            *reinterpret_cast<ushort2*>(rowp + 64 + l15 * 2) = ft;
        }
    }
    __syncthreads();

    // ---- phase 2: GEMM1  h^T = W1^T @ comb^T ----
    {
        f32x4 acc1[4][4];                       // [r(hid-tile)][mt(pt-tile)]
        #pragma unroll
        for (int r = 0; r < 4; ++r)
            #pragma unroll
            for (int mt = 0; mt < 4; ++mt) acc1[r][mt] = (f32x4)0.f;

        #pragma unroll
        for (int ks = 0; ks < 3; ++ks) {
            bf16x8 af[4], bfr[4];
            #pragma unroll
            for (int r = 0; r < 4; ++r) {
                const int rt = w * 4 + r;
                af[r] = *reinterpret_cast<const bf16x8*>(
                            ws + (size_t)((rt * 3 + ks) * 64 + lane) * 8);
            }
            #pragma unroll
            for (int mt = 0; mt < 4; ++mt)
                bfr[mt] = *reinterpret_cast<const bf16x8*>(
                            &comb[(mt * 16 + l15) * CSTR + ks * 32 + l4 * 8]);
            #pragma unroll
            for (int r = 0; r < 4; ++r)
                #pragma unroll
                for (int mt = 0; mt < 4; ++mt)
                    acc1[r][mt] = __builtin_amdgcn_mfma_f32_16x16x32_bf16(
                                      af[r], bfr[mt], acc1[r][mt], 0, 0, 0);
        }

        // bias + relu -> hbuf[m][hid] (bf16)
        #pragma unroll
        for (int r = 0; r < 4; ++r) {
            const int hid0 = (w * 4 + r) * 16 + l4 * 4;
            const float4 bv = *reinterpret_cast<const float4*>(b1 + hid0);
            #pragma unroll
            for (int mt = 0; mt < 4; ++mt) {
                const int m = mt * 16 + l15;
                ushort4 hv;
                hv.x = f2b(fmaxf(acc1[r][mt][0] + bv.x, 0.f));
                hv.y = f2b(fmaxf(acc1[r][mt][1] + bv.y, 0.f));
                hv.z = f2b(fmaxf(acc1[r][mt][2] + bv.z, 0.f));
                hv.w = f2b(fmaxf(acc1[r][mt][3] + bv.w, 0.f));
                *reinterpret_cast<ushort4*>(&hbuf[m * HSTR + hid0]) = hv;
            }
        }
    }
    __syncthreads();

    // ---- phase 3: GEMM2 transposed  out^T = W2^T @ h^T ----
    {
        f32x4 acc2[4][4];                       // [mt(pt-tile)][c(outcol-tile)]
        #pragma unroll
        for (int mt = 0; mt < 4; ++mt)
            #pragma unroll
            for (int c = 0; c < 4; ++c) acc2[mt][c] = (f32x4)0.f;

        #pragma unroll
        for (int ks = 0; ks < 8; ++ks) {
            bf16x8 hf[4], wf[4];
            #pragma unroll
            for (int mt = 0; mt < 4; ++mt)
                hf[mt] = *reinterpret_cast<const bf16x8*>(
                            &hbuf[(mt * 16 + l15) * HSTR + ks * 32 + l4 * 8]);
            #pragma unroll
            for (int c = 0; c < 4; ++c) {
                const int ct = w * 4 + c;
                wf[c] = *reinterpret_cast<const bf16x8*>(
                            ws + (size_t)(WSA1_N + ((ct * 8 + ks) * 64 + lane) * 8));
            }
            #pragma unroll
            for (int mt = 0; mt < 4; ++mt)
                #pragma unroll
                for (int c = 0; c < 4; ++c)
                    acc2[mt][c] = __builtin_amdgcn_mfma_f32_16x16x32_bf16(
                                      wf[c], hf[mt], acc2[mt][c], 0, 0, 0);
        }

        // epilogue: lane holds 4 consecutive out cols for one point -> float4
        #pragma unroll
        for (int c = 0; c < 4; ++c) {
            const int col0 = (w * 4 + c) * 16 + l4 * 4;
            const float4 bv = *reinterpret_cast<const float4*>(b2 + col0);
            #pragma unroll
            for (int mt = 0; mt < 4; ++mt) {
                const int p = p0 + mt * 16 + l15;
                if (p < kPts) {
                    float4 o;
                    o.x = acc2[mt][c][0] + bv.x;
                    o.y = acc2[mt][c][1] + bv.y;
                    o.z = acc2[mt][c][2] + bv.z;
                    o.w = acc2[mt][c][3] + bv.w;
                    *reinterpret_cast<float4*>(out + (size_t)p * kOut + col0) = o;
                }
            }
        }
    }
}

extern "C" void kernel_launch(void* const* d_in, const int* in_sizes, int n_in,
                              void* d_out, int out_size, void* d_ws, size_t ws_size,
                              hipStream_t stream) {
    const float* grid    = (const float*)d_in[0];
    const float* mfeat   = (const float*)d_in[1];
    const int*   indices = (const int*)d_in[2];
    const float* weights = (const float*)d_in[3];
    const float* W1      = (const float*)d_in[4];
    const float* b1      = (const float*)d_in[5];
    const float* W2      = (const float*)d_in[6];
    const float* b2      = (const float*)d_in[7];
    float* o = (float*)d_out;

    if (ws_size >= WS_BYTES) {
        ushort* ws = (ushort*)d_ws;
        g2m_prep<<<44, 256, 0, stream>>>(W1, W2, ws);
        g2m_fused2<<<NBLKB, 256, 0, stream>>>(grid, mfeat, indices, weights,
                                              b1, b2, ws, o);
    }
}